// Round 3
// baseline (180.515 us; speedup 1.0000x reference)
//
#include <hip/hip_runtime.h>
#include <math.h>

#define B_ 2
#define C_ 128
#define H_ 64
#define W_ 64
#define F_ 16
#define U_ 9
#define MD_ 4
#define UV_ 81
#define HW_ (H_*W_)
#define BF_ (B_*F_)

// cvol layout in workspace: cvol[uv][bf][pix], bf = b*F_+f
// out0 layout: out0[bf][ch][pix], ch in {flowx, flowy, local_ent, global_ent}

__global__ __launch_bounds__(256)
void cvol_kernel(const float* __restrict__ ref,
                 const float* __restrict__ tar,
                 const float* __restrict__ pw,
                 float* __restrict__ cvol) {
    int t = threadIdx.x;
    int pix0 = (blockIdx.x * 256 + t) * 4;   // 4 consecutive pixels per thread
    int uv  = blockIdx.y;                    // u = x-shift idx, v = y-shift idx
    int b   = blockIdx.z;
    int y = pix0 >> 6, x0 = pix0 & 63;
    int du = uv / U_ - MD_;                  // x displacement
    int dv = uv % U_ - MD_;                  // y displacement
    int ys = y + dv;
    bool rowv = ((unsigned)ys < (unsigned)H_);
    int ysc = rowv ? ys : 0;

    const float* rp = ref + (size_t)b * C_ * HW_ + pix0;
    const float* tp = tar + (size_t)b * C_ * HW_ + ysc * W_;

    int xc[4]; float msk[4];
#pragma unroll
    for (int i = 0; i < 4; ++i) {
        int xs = x0 + du + i;
        bool v = rowv && ((unsigned)xs < (unsigned)W_);
        xc[i] = xs < 0 ? 0 : (xs > W_ - 1 ? W_ - 1 : xs);
        msk[i] = v ? 1.f : 0.f;
    }

    float acc[F_][4];
#pragma unroll
    for (int f = 0; f < F_; ++f)
#pragma unroll
        for (int i = 0; i < 4; ++i) acc[f][i] = 0.f;

#pragma unroll 2
    for (int c = 0; c < C_; ++c) {
        float4 rv = *(const float4*)(rp + (size_t)c * HW_);
        const float* tc = tp + (size_t)c * HW_;
        float tv0 = tc[xc[0]] * msk[0];
        float tv1 = tc[xc[1]] * msk[1];
        float tv2 = tc[xc[2]] * msk[2];
        float tv3 = tc[xc[3]] * msk[3];
        float p0 = rv.x * tv0; p0 = fmaxf(p0, 0.1f * p0);   // leaky_relu(.,0.1)
        float p1 = rv.y * tv1; p1 = fmaxf(p1, 0.1f * p1);
        float p2 = rv.z * tv2; p2 = fmaxf(p2, 0.1f * p2);
        float p3 = rv.w * tv3; p3 = fmaxf(p3, 0.1f * p3);
#pragma unroll
        for (int f = 0; f < F_; ++f) {
            float w = pw[f * C_ + c];        // uniform address -> s_load (K$)
            acc[f][0] = fmaf(w, p0, acc[f][0]);
            acc[f][1] = fmaf(w, p1, acc[f][1]);
            acc[f][2] = fmaf(w, p2, acc[f][2]);
            acc[f][3] = fmaf(w, p3, acc[f][3]);
        }
    }

    float* op = cvol + ((size_t)uv * BF_ + (size_t)b * F_) * HW_ + pix0;
#pragma unroll
    for (int f = 0; f < F_; ++f) {
        *(float4*)(op + (size_t)f * HW_) =
            make_float4(acc[f][0], acc[f][1], acc[f][2], acc[f][3]);
    }
}

__global__ __launch_bounds__(256)
void flowreg_kernel(const float* __restrict__ cvol,
                    float* __restrict__ out0) {
    int tid = blockIdx.x * 256 + threadIdx.x;   // over BF_*HW_
    int pix = tid & (HW_ - 1);
    int bf  = tid >> 12;                        // HW_ = 4096
    const float* cp = cvol + (size_t)bf * HW_ + pix;
    const size_t stride = (size_t)BF_ * HW_;

    // single load round: cache all 81 uv values in registers
    float v[UV_];
#pragma unroll
    for (int uv = 0; uv < UV_; ++uv) v[uv] = cp[(size_t)uv * stride];

    // argmax (first occurrence, matching jnp.argmax)
    float m = v[0]; int best = 0;
#pragma unroll
    for (int uv = 1; uv < UV_; ++uv) {
        if (v[uv] > m) { m = v[uv]; best = uv; }
    }
    int ub = best / U_;   // x-shift index of argmax
    int vb = best - ub * U_;

    float S = 0.f, A = 0.f, Sx = 0.f, Sy = 0.f, gS = 0.f, gA = 0.f;
#pragma unroll
    for (int uv = 0; uv < UV_; ++uv) {
        float d = v[uv] - m;
        float z = __expf(d);
        gS += z; gA = fmaf(z, d, gA);
        int u = uv / U_, vy = uv - u * U_;      // compile-time constants
        int duc = u - ub, dvc = vy - vb;
        bool msk = (duc <= 3) && (duc >= -3) && (dvc <= 3) && (dvc >= -3);
        float zm = msk ? z : 0.f;
        float dm = msk ? d : 0.f;
        S += zm;
        A = fmaf(zm, dm, A);
        Sx = fmaf(zm, (float)(u - MD_), Sx);
        Sy = fmaf(zm, (float)(vy - MD_), Sy);
    }
    float invS = 1.f / S;
    float outx = Sx * invS;
    float outy = Sy * invS;
    // sum p*log p = A/S - log S  (p = z/S, log p = d - log S)
    float lent = (logf(S)  - A * invS) * (1.0f / logf(49.0f));
    float gent = (logf(gS) - gA / gS)  * (1.0f / logf(81.0f));

    float* op = out0 + (size_t)bf * 4 * HW_ + pix;
    op[0 * HW_] = outx;
    op[1 * HW_] = outy;
    op[2 * HW_] = lent;
    op[3 * HW_] = gent;
}

__global__ __launch_bounds__(256)
void warp_kernel(const float* __restrict__ tar,
                 const float* __restrict__ out0,
                 float* __restrict__ warped) {
    int tid = blockIdx.x * 256 + threadIdx.x;   // over B_*C_*HW_
    int pix = tid & (HW_ - 1);
    int bc  = tid >> 12;
    int b   = bc >> 7;                          // C_ = 128
    int x = pix & 63, y = pix >> 6;

    // flow = hypothesis f=0 of out0 for this b
    const float* fbase = out0 + (size_t)(b * F_) * 4 * HW_;
    float fx = fbase[pix];
    float fy = fbase[HW_ + pix];
    float px = (float)x + fx;
    float py = (float)y + fy;

    bool inb = (fabsf(2.0f * px / (float)(W_ - 1) - 1.0f) < 1.0f) &&
               (fabsf(2.0f * py / (float)(H_ - 1) - 1.0f) < 1.0f);

    float x0 = floorf(px), y0 = floorf(py);
    float wx = px - x0,    wy = py - y0;
    int x0i = (int)x0, y0i = (int)y0;

    const float* img = tar + (size_t)bc * HW_;

    auto tap = [&](int yi, int xi, float wgt) -> float {
        bool v = ((unsigned)xi < (unsigned)W_) && ((unsigned)yi < (unsigned)H_);
        int xc = xi < 0 ? 0 : (xi > W_ - 1 ? W_ - 1 : xi);
        int yc = yi < 0 ? 0 : (yi > H_ - 1 ? H_ - 1 : yi);
        float val = img[yc * W_ + xc];
        return val * (v ? wgt : 0.f);
    };

    float acc = tap(y0i,     x0i,     (1.f - wx) * (1.f - wy))
              + tap(y0i,     x0i + 1, wx * (1.f - wy))
              + tap(y0i + 1, x0i,     (1.f - wx) * wy)
              + tap(y0i + 1, x0i + 1, wx * wy);

    warped[tid] = inb ? acc : 0.f;
}

extern "C" void kernel_launch(void* const* d_in, const int* in_sizes, int n_in,
                              void* d_out, int out_size, void* d_ws, size_t ws_size,
                              hipStream_t stream) {
    const float* ref = (const float*)d_in[0];
    const float* tar = (const float*)d_in[1];
    const float* pw  = (const float*)d_in[2];
    float* out0 = (float*)d_out;                       // (B*F, 4, H, W) = 524288 floats
    float* out1 = out0 + (size_t)BF_ * 4 * HW_;        // (B, C, H, W)  = 2097152 floats
    float* cvol = (float*)d_ws;                        // 81*32*4096 floats = 42.5 MB

    dim3 g1(HW_ / (256 * 4), UV_, B_);                 // 4 pixels per thread
    cvol_kernel<<<g1, 256, 0, stream>>>(ref, tar, pw, cvol);
    flowreg_kernel<<<(BF_ * HW_) / 256, 256, 0, stream>>>(cvol, out0);
    warp_kernel<<<(B_ * C_ * HW_) / 256, 256, 0, stream>>>(tar, out0, out1);
}

// Round 4
// 177.664 us; speedup vs baseline: 1.0160x; 1.0160x over previous
//
#include <hip/hip_runtime.h>
#include <math.h>

#define B_ 2
#define C_ 128
#define H_ 64
#define W_ 64
#define F_ 16
#define U_ 9
#define MD_ 4
#define UV_ 81
#define HW_ (H_*W_)
#define BF_ (B_*F_)

// cvol layout in workspace: cvol[uv][bf][pix], bf = b*F_+f, uv = u*9+v
//   (u = x-shift index, v = y-shift index; displacement du=u-4, dv=v-4)
// out0 layout: out0[bf][ch][pix], ch in {flowx, flowy, local_ent, global_ent}

// wave = one image row (W=64 lanes). One block = 1 wave, handles one y row,
// one dv (y-shift), and NG consecutive u values (x-shifts) via __shfl.
template<int U0, int NG>
__global__ __launch_bounds__(64)
void cvol_kernel(const float* __restrict__ ref,
                 const float* __restrict__ tar,
                 const float* __restrict__ pw,
                 float* __restrict__ cvol) {
    const int x    = threadIdx.x;        // 0..63 = pixel x = lane
    const int y    = blockIdx.x;         // 0..63 row
    const int vidx = blockIdx.y;         // 0..8  y-shift index
    const int b    = blockIdx.z;
    const int dv   = vidx - MD_;
    const int ys   = y + dv;
    const bool rowv = ((unsigned)ys < (unsigned)H_);
    const int ysc  = rowv ? ys : 0;

    const float* rp = ref + (size_t)b * C_ * HW_ + y  * W_ + x;
    const float* tp = tar + (size_t)b * C_ * HW_ + ysc * W_ + x;

    // per-du x-validity masks (held in scalar mask regs by the compiler)
    bool xv[NG];
#pragma unroll
    for (int i = 0; i < NG; ++i) {
        int du = U0 + i - MD_;
        xv[i] = ((unsigned)(x + du) < (unsigned)W_);
    }

    float acc[NG][F_];
#pragma unroll
    for (int i = 0; i < NG; ++i)
#pragma unroll
        for (int f = 0; f < F_; ++f) acc[i][f] = 0.f;

#pragma unroll 2
    for (int c = 0; c < C_; ++c) {
        float rv = rp[(size_t)c * HW_];          // coalesced row load
        float tr = tp[(size_t)c * HW_];          // coalesced row load (clamped row)
        tr = rowv ? tr : 0.f;                    // zero padding for OOB row
#pragma unroll
        for (int i = 0; i < NG; ++i) {
            int du = U0 + i - MD_;
            float tv = __shfl(tr, x + du);       // x-shift via ds_bpermute
            tv = xv[i] ? tv : 0.f;               // zero padding for OOB col
            float p = rv * tv;
            p = fmaxf(p, 0.1f * p);              // leaky_relu(.,0.1); lrelu(0)=0
#pragma unroll
            for (int f = 0; f < F_; ++f) {
                float w = pw[f * C_ + c];        // uniform -> scalar K$ load
                acc[i][f] = fmaf(w, p, acc[i][f]);
            }
        }
    }

#pragma unroll
    for (int i = 0; i < NG; ++i) {
        int plane = (U0 + i) * U_ + vidx;        // uv = u*9 + v
        float* op = cvol + ((size_t)plane * BF_ + (size_t)b * F_) * HW_ + y * W_ + x;
#pragma unroll
        for (int f = 0; f < F_; ++f) op[(size_t)f * HW_] = acc[i][f];
    }
}

__global__ __launch_bounds__(256)
void flowreg_kernel(const float* __restrict__ cvol,
                    float* __restrict__ out0) {
    int tid = blockIdx.x * 256 + threadIdx.x;   // over BF_*HW_
    int pix = tid & (HW_ - 1);
    int bf  = tid >> 12;                        // HW_ = 4096
    const float* cp = cvol + (size_t)bf * HW_ + pix;
    const size_t stride = (size_t)BF_ * HW_;

    // single load round: cache all 81 uv values in registers
    float v[UV_];
#pragma unroll
    for (int uv = 0; uv < UV_; ++uv) v[uv] = cp[(size_t)uv * stride];

    // argmax (first occurrence, matching jnp.argmax)
    float m = v[0]; int best = 0;
#pragma unroll
    for (int uv = 1; uv < UV_; ++uv) {
        if (v[uv] > m) { m = v[uv]; best = uv; }
    }
    int ub = best / U_;   // x-shift index of argmax
    int vb = best - ub * U_;

    float S = 0.f, A = 0.f, Sx = 0.f, Sy = 0.f, gS = 0.f, gA = 0.f;
#pragma unroll
    for (int uv = 0; uv < UV_; ++uv) {
        float d = v[uv] - m;
        float z = __expf(d);
        gS += z; gA = fmaf(z, d, gA);
        int u = uv / U_, vy = uv - u * U_;      // compile-time constants
        int duc = u - ub, dvc = vy - vb;
        bool msk = (duc <= 3) && (duc >= -3) && (dvc <= 3) && (dvc >= -3);
        float zm = msk ? z : 0.f;
        float dm = msk ? d : 0.f;
        S += zm;
        A = fmaf(zm, dm, A);
        Sx = fmaf(zm, (float)(u - MD_), Sx);
        Sy = fmaf(zm, (float)(vy - MD_), Sy);
    }
    float invS = 1.f / S;
    float outx = Sx * invS;
    float outy = Sy * invS;
    // sum p*log p = A/S - log S  (p = z/S, log p = d - log S)
    float lent = (logf(S)  - A * invS) * (1.0f / logf(49.0f));
    float gent = (logf(gS) - gA / gS)  * (1.0f / logf(81.0f));

    float* op = out0 + (size_t)bf * 4 * HW_ + pix;
    op[0 * HW_] = outx;
    op[1 * HW_] = outy;
    op[2 * HW_] = lent;
    op[3 * HW_] = gent;
}

__global__ __launch_bounds__(256)
void warp_kernel(const float* __restrict__ tar,
                 const float* __restrict__ out0,
                 float* __restrict__ warped) {
    int tid = blockIdx.x * 256 + threadIdx.x;   // over B_*C_*HW_
    int pix = tid & (HW_ - 1);
    int bc  = tid >> 12;
    int b   = bc >> 7;                          // C_ = 128
    int x = pix & 63, y = pix >> 6;

    // flow = hypothesis f=0 of out0 for this b
    const float* fbase = out0 + (size_t)(b * F_) * 4 * HW_;
    float fx = fbase[pix];
    float fy = fbase[HW_ + pix];
    float px = (float)x + fx;
    float py = (float)y + fy;

    bool inb = (fabsf(2.0f * px / (float)(W_ - 1) - 1.0f) < 1.0f) &&
               (fabsf(2.0f * py / (float)(H_ - 1) - 1.0f) < 1.0f);

    float x0 = floorf(px), y0 = floorf(py);
    float wx = px - x0,    wy = py - y0;
    int x0i = (int)x0, y0i = (int)y0;

    const float* img = tar + (size_t)bc * HW_;

    auto tap = [&](int yi, int xi, float wgt) -> float {
        bool v = ((unsigned)xi < (unsigned)W_) && ((unsigned)yi < (unsigned)H_);
        int xc = xi < 0 ? 0 : (xi > W_ - 1 ? W_ - 1 : xi);
        int yc = yi < 0 ? 0 : (yi > H_ - 1 ? H_ - 1 : yi);
        float val = img[yc * W_ + xc];
        return val * (v ? wgt : 0.f);
    };

    float acc = tap(y0i,     x0i,     (1.f - wx) * (1.f - wy))
              + tap(y0i,     x0i + 1, wx * (1.f - wy))
              + tap(y0i + 1, x0i,     (1.f - wx) * wy)
              + tap(y0i + 1, x0i + 1, wx * wy);

    warped[tid] = inb ? acc : 0.f;
}

extern "C" void kernel_launch(void* const* d_in, const int* in_sizes, int n_in,
                              void* d_out, int out_size, void* d_ws, size_t ws_size,
                              hipStream_t stream) {
    const float* ref = (const float*)d_in[0];
    const float* tar = (const float*)d_in[1];
    const float* pw  = (const float*)d_in[2];
    float* out0 = (float*)d_out;                       // (B*F, 4, H, W) = 524288 floats
    float* out1 = out0 + (size_t)BF_ * 4 * HW_;        // (B, C, H, W)  = 2097152 floats
    float* cvol = (float*)d_ws;                        // 81*32*4096 floats = 42.5 MB

    dim3 gc(H_, U_, B_);                               // (row, dv, batch), 1 wave/block
    cvol_kernel<0, 5><<<gc, 64, 0, stream>>>(ref, tar, pw, cvol);  // u = 0..4
    cvol_kernel<5, 4><<<gc, 64, 0, stream>>>(ref, tar, pw, cvol);  // u = 5..8
    flowreg_kernel<<<(BF_ * HW_) / 256, 256, 0, stream>>>(cvol, out0);
    warp_kernel<<<(B_ * C_ * HW_) / 256, 256, 0, stream>>>(tar, out0, out1);
}

// Round 5
// 130.487 us; speedup vs baseline: 1.3834x; 1.3615x over previous
//
#include <hip/hip_runtime.h>
#include <math.h>

#define B_ 2
#define C_ 128
#define H_ 64
#define W_ 64
#define F_ 16
#define U_ 9
#define MD_ 4
#define UV_ 81
#define HW_ (H_*W_)
#define BF_ (B_*F_)

// cvol layout in workspace: cvol[uv][bf][pix], bf = b*F_+f, uv = u*9+v
//   (u = x-shift index, v = y-shift index; displacement du=u-4, dv=v-4)
// out0 layout: out0[bf][ch][pix], ch in {flowx, flowy, local_ent, global_ent}

// wave = one image row (W=64 lanes). Block = 4 waves = 4 consecutive rows.
// blockIdx.z encodes (b, u-group of NG=3 x-shifts). All 9 dv in blockIdx.y.
// Single launch -> 864 blocks / 3456 waves, 13.5 waves/CU concurrent.
#define NG_ 3
__global__ __launch_bounds__(256)
void cvol_kernel(const float* __restrict__ ref,
                 const float* __restrict__ tar,
                 const float* __restrict__ pw,
                 float* __restrict__ cvol) {
    const int t    = threadIdx.x;
    const int x    = t & 63;             // lane = pixel x
    const int y    = blockIdx.x * 4 + (t >> 6);   // wave = row
    const int vidx = blockIdx.y;         // 0..8  y-shift index
    const int z    = blockIdx.z;         // 0..5 = b*3 + group
    const int b    = z / 3;
    const int U0   = (z - b * 3) * NG_;  // first x-shift index of this group
    const int dv   = vidx - MD_;
    const int ys   = y + dv;
    const bool rowv = ((unsigned)ys < (unsigned)H_);
    const int ysc  = rowv ? ys : 0;

    const float* rp = ref + (size_t)b * C_ * HW_ + y  * W_ + x;
    const float* tp = tar + (size_t)b * C_ * HW_ + ysc * W_ + x;

    bool xv[NG_];
#pragma unroll
    for (int i = 0; i < NG_; ++i) {
        int du = U0 + i - MD_;
        xv[i] = ((unsigned)(x + du) < (unsigned)W_);
    }

    float acc[NG_][F_];
#pragma unroll
    for (int i = 0; i < NG_; ++i)
#pragma unroll
        for (int f = 0; f < F_; ++f) acc[i][f] = 0.f;

#pragma unroll 4
    for (int c = 0; c < C_; ++c) {
        float rv = rp[(size_t)c * HW_];          // coalesced row load
        float tr = tp[(size_t)c * HW_];          // coalesced row load (clamped row)
        tr = rowv ? tr : 0.f;                    // zero padding for OOB row
#pragma unroll
        for (int i = 0; i < NG_; ++i) {
            int du = U0 + i - MD_;
            float tv = __shfl(tr, x + du);       // x-shift via ds_bpermute
            tv = xv[i] ? tv : 0.f;               // zero padding for OOB col
            float p = rv * tv;
            p = fmaxf(p, 0.1f * p);              // leaky_relu(.,0.1); lrelu(0)=0
#pragma unroll
            for (int f = 0; f < F_; ++f) {
                float w = pw[f * C_ + c];        // uniform -> scalar K$ load
                acc[i][f] = fmaf(w, p, acc[i][f]);
            }
        }
    }

#pragma unroll
    for (int i = 0; i < NG_; ++i) {
        int plane = (U0 + i) * U_ + vidx;        // uv = u*9 + v
        float* op = cvol + ((size_t)plane * BF_ + (size_t)b * F_) * HW_ + y * W_ + x;
#pragma unroll
        for (int f = 0; f < F_; ++f) op[(size_t)f * HW_] = acc[i][f];
    }
}

__global__ __launch_bounds__(256)
void flowreg_kernel(const float* __restrict__ cvol,
                    float* __restrict__ out0) {
    int tid = blockIdx.x * 256 + threadIdx.x;   // over BF_*HW_
    int pix = tid & (HW_ - 1);
    int bf  = tid >> 12;                        // HW_ = 4096
    const float* cp = cvol + (size_t)bf * HW_ + pix;
    const size_t stride = (size_t)BF_ * HW_;

    // single load round: cache all 81 uv values in registers
    float v[UV_];
#pragma unroll
    for (int uv = 0; uv < UV_; ++uv) v[uv] = cp[(size_t)uv * stride];

    // argmax (first occurrence, matching jnp.argmax)
    float m = v[0]; int best = 0;
#pragma unroll
    for (int uv = 1; uv < UV_; ++uv) {
        if (v[uv] > m) { m = v[uv]; best = uv; }
    }
    int ub = best / U_;   // x-shift index of argmax
    int vb = best - ub * U_;

    float S = 0.f, A = 0.f, Sx = 0.f, Sy = 0.f, gS = 0.f, gA = 0.f;
#pragma unroll
    for (int uv = 0; uv < UV_; ++uv) {
        float d = v[uv] - m;
        float z = __expf(d);
        gS += z; gA = fmaf(z, d, gA);
        int u = uv / U_, vy = uv - u * U_;      // compile-time constants
        int duc = u - ub, dvc = vy - vb;
        bool msk = (duc <= 3) && (duc >= -3) && (dvc <= 3) && (dvc >= -3);
        float zm = msk ? z : 0.f;
        float dm = msk ? d : 0.f;
        S += zm;
        A = fmaf(zm, dm, A);
        Sx = fmaf(zm, (float)(u - MD_), Sx);
        Sy = fmaf(zm, (float)(vy - MD_), Sy);
    }
    float invS = 1.f / S;
    float outx = Sx * invS;
    float outy = Sy * invS;
    // sum p*log p = A/S - log S  (p = z/S, log p = d - log S)
    float lent = (logf(S)  - A * invS) * (1.0f / logf(49.0f));
    float gent = (logf(gS) - gA / gS)  * (1.0f / logf(81.0f));

    float* op = out0 + (size_t)bf * 4 * HW_ + pix;
    op[0 * HW_] = outx;
    op[1 * HW_] = outy;
    op[2 * HW_] = lent;
    op[3 * HW_] = gent;
}

__global__ __launch_bounds__(256)
void warp_kernel(const float* __restrict__ tar,
                 const float* __restrict__ out0,
                 float* __restrict__ warped) {
    int tid = blockIdx.x * 256 + threadIdx.x;   // over B_*C_*HW_
    int pix = tid & (HW_ - 1);
    int bc  = tid >> 12;
    int b   = bc >> 7;                          // C_ = 128
    int x = pix & 63, y = pix >> 6;

    // flow = hypothesis f=0 of out0 for this b
    const float* fbase = out0 + (size_t)(b * F_) * 4 * HW_;
    float fx = fbase[pix];
    float fy = fbase[HW_ + pix];
    float px = (float)x + fx;
    float py = (float)y + fy;

    bool inb = (fabsf(2.0f * px / (float)(W_ - 1) - 1.0f) < 1.0f) &&
               (fabsf(2.0f * py / (float)(H_ - 1) - 1.0f) < 1.0f);

    float x0 = floorf(px), y0 = floorf(py);
    float wx = px - x0,    wy = py - y0;
    int x0i = (int)x0, y0i = (int)y0;

    const float* img = tar + (size_t)bc * HW_;

    auto tap = [&](int yi, int xi, float wgt) -> float {
        bool v = ((unsigned)xi < (unsigned)W_) && ((unsigned)yi < (unsigned)H_);
        int xc = xi < 0 ? 0 : (xi > W_ - 1 ? W_ - 1 : xi);
        int yc = yi < 0 ? 0 : (yi > H_ - 1 ? H_ - 1 : yi);
        float val = img[yc * W_ + xc];
        return val * (v ? wgt : 0.f);
    };

    float acc = tap(y0i,     x0i,     (1.f - wx) * (1.f - wy))
              + tap(y0i,     x0i + 1, wx * (1.f - wy))
              + tap(y0i + 1, x0i,     (1.f - wx) * wy)
              + tap(y0i + 1, x0i + 1, wx * wy);

    warped[tid] = inb ? acc : 0.f;
}

extern "C" void kernel_launch(void* const* d_in, const int* in_sizes, int n_in,
                              void* d_out, int out_size, void* d_ws, size_t ws_size,
                              hipStream_t stream) {
    const float* ref = (const float*)d_in[0];
    const float* tar = (const float*)d_in[1];
    const float* pw  = (const float*)d_in[2];
    float* out0 = (float*)d_out;                       // (B*F, 4, H, W) = 524288 floats
    float* out1 = out0 + (size_t)BF_ * 4 * HW_;        // (B, C, H, W)  = 2097152 floats
    float* cvol = (float*)d_ws;                        // 81*32*4096 floats = 42.5 MB

    dim3 gc(H_ / 4, U_, B_ * 3);                       // (row-quad, dv, b*3+ugroup)
    cvol_kernel<<<gc, 256, 0, stream>>>(ref, tar, pw, cvol);
    flowreg_kernel<<<(BF_ * HW_) / 256, 256, 0, stream>>>(cvol, out0);
    warp_kernel<<<(B_ * C_ * HW_) / 256, 256, 0, stream>>>(tar, out0, out1);
}

// Round 6
// 127.849 us; speedup vs baseline: 1.4119x; 1.0206x over previous
//
#include <hip/hip_runtime.h>
#include <math.h>

#define B_ 2
#define C_ 128
#define H_ 64
#define W_ 64
#define F_ 16
#define U_ 9
#define MD_ 4
#define UV_ 81
#define HW_ (H_*W_)
#define BF_ (B_*F_)

typedef float v2f __attribute__((ext_vector_type(2)));

// cvol layout in workspace: cvol[uv][bf][pix], bf = b*F_+f, uv = u*9+v
//   (u = x-shift index, v = y-shift index; displacement du=u-4, dv=v-4)
// out0 layout: out0[bf][ch][pix], ch in {flowx, flowy, local_ent, global_ent}

// wave = one image row (W=64 lanes). Block = 4 waves = 4 consecutive rows.
// blockIdx.z encodes (b, u-group of NG=3 x-shifts). All 9 dv in blockIdx.y.
#define NG_ 3
__global__ __launch_bounds__(256)
void cvol_kernel(const float* __restrict__ ref,
                 const float* __restrict__ tar,
                 const float* __restrict__ pw,
                 float* __restrict__ cvol) {
    const int t    = threadIdx.x;
    const int x    = t & 63;             // lane = pixel x
    const int y    = blockIdx.x * 4 + (t >> 6);   // wave = row
    const int vidx = blockIdx.y;         // 0..8  y-shift index
    const int z    = blockIdx.z;         // 0..5 = b*3 + group
    const int b    = z / 3;
    const int U0   = (z - b * 3) * NG_;  // first x-shift index of this group
    const int dv   = vidx - MD_;
    const int ys   = y + dv;
    const bool rowv = ((unsigned)ys < (unsigned)H_);
    const int ysc  = rowv ? ys : 0;

    const float* rp = ref + (size_t)b * C_ * HW_ + y  * W_ + x;
    const float* tp = tar + (size_t)b * C_ * HW_ + ysc * W_ + x;

    bool xv[NG_];
#pragma unroll
    for (int i = 0; i < NG_; ++i) {
        int du = U0 + i - MD_;
        xv[i] = ((unsigned)(x + du) < (unsigned)W_);
    }

    v2f acc[NG_][F_ / 2];
#pragma unroll
    for (int i = 0; i < NG_; ++i)
#pragma unroll
        for (int h = 0; h < F_ / 2; ++h) acc[i][h] = (v2f)0.f;

#pragma unroll 4
    for (int c = 0; c < C_; ++c) {
        float rv = rp[(size_t)c * HW_];          // coalesced row load
        float tr = tp[(size_t)c * HW_];          // coalesced row load (clamped row)
        tr = rowv ? tr : 0.f;                    // zero padding for OOB row

        v2f wv[F_ / 2];                          // uniform -> scalar K$ loads
#pragma unroll
        for (int h = 0; h < F_ / 2; ++h) {
            wv[h].x = pw[(2 * h + 0) * C_ + c];
            wv[h].y = pw[(2 * h + 1) * C_ + c];
        }
#pragma unroll
        for (int i = 0; i < NG_; ++i) {
            int du = U0 + i - MD_;
            float tv = __shfl(tr, x + du);       // x-shift via ds_bpermute
            tv = xv[i] ? tv : 0.f;               // zero padding for OOB col
            float p = rv * tv;
            p = fmaxf(p, 0.1f * p);              // leaky_relu(.,0.1)
            v2f pv = {p, p};
#pragma unroll
            for (int h = 0; h < F_ / 2; ++h)     // v_pk_fma_f32: 2 FMA / instr
                acc[i][h] = __builtin_elementwise_fma(wv[h], pv, acc[i][h]);
        }
    }

#pragma unroll
    for (int i = 0; i < NG_; ++i) {
        int plane = (U0 + i) * U_ + vidx;        // uv = u*9 + v
        float* op = cvol + ((size_t)plane * BF_ + (size_t)b * F_) * HW_ + y * W_ + x;
#pragma unroll
        for (int h = 0; h < F_ / 2; ++h) {
            op[(size_t)(2 * h + 0) * HW_] = acc[i][h].x;
            op[(size_t)(2 * h + 1) * HW_] = acc[i][h].y;
        }
    }
}

// 4 threads per pixel, each owning a chunk of the 81 uv-planes.
// chunks (ascending uv): j=0 -> [0,21), j=1 -> [21,41), j=2 -> [41,61), j=3 -> [61,81)
__global__ __launch_bounds__(256)
void flowreg_kernel(const float* __restrict__ cvol,
                    float* __restrict__ out0) {
    const int lane = threadIdx.x & 63;
    const int j    = threadIdx.x >> 6;              // 0..3 = uv chunk = wave id
    const int blk  = blockIdx.x;                    // over BF_*HW_/64 = 2048
    const int bf   = blk >> 6;                      // 64 blocks per bf
    const int pix  = (blk & 63) * 64 + lane;

    const float* cp = cvol + (size_t)bf * HW_ + pix;
    const size_t stride = (size_t)BF_ * HW_;

    const int start = (j == 0) ? 0 : (1 + j * 20);
    const int n     = (j == 0) ? 21 : 20;

    float v[21];
#pragma unroll 21
    for (int i = 0; i < n; ++i) v[i] = cp[(size_t)(start + i) * stride];

    // local argmax (ascending, strict > keeps first occurrence)
    float mv = v[0]; int bi = start;
#pragma unroll 21
    for (int i = 1; i < n; ++i) {
        if (v[i] > mv) { mv = v[i]; bi = start + i; }
    }

    __shared__ float smax[4][64];
    __shared__ int   sidx[4][64];
    smax[j][lane] = mv; sidx[j][lane] = bi;
    __syncthreads();

    // combine chunks ascending -> global first-occurrence argmax (all threads)
    float m = smax[0][lane]; int best = sidx[0][lane];
#pragma unroll
    for (int k = 1; k < 4; ++k) {
        float vv = smax[k][lane];
        if (vv > m) { m = vv; best = sidx[k][lane]; }
    }
    int ub = best / U_;           // x-shift index of argmax
    int vb = best - ub * U_;      // y-shift index

    float S = 0.f, A = 0.f, Sx = 0.f, Sy = 0.f, gS = 0.f, gA = 0.f;
#pragma unroll 21
    for (int i = 0; i < n; ++i) {
        int uv = start + i;
        float d = v[i] - m;
        float z = __expf(d);
        gS += z; gA = fmaf(z, d, gA);
        int u = uv / U_, vy = uv - u * U_;
        int duc = u - ub, dvc = vy - vb;
        bool msk = (duc <= 3) && (duc >= -3) && (dvc <= 3) && (dvc >= -3);
        float zm = msk ? z : 0.f;
        float dm = msk ? d : 0.f;
        S += zm;
        A = fmaf(zm, dm, A);
        Sx = fmaf(zm, (float)(u - MD_), Sx);
        Sy = fmaf(zm, (float)(vy - MD_), Sy);
    }

    __shared__ float sred[6][4][64];
    sred[0][j][lane] = S;  sred[1][j][lane] = A;
    sred[2][j][lane] = Sx; sred[3][j][lane] = Sy;
    sred[4][j][lane] = gS; sred[5][j][lane] = gA;
    __syncthreads();

    if (j == 0) {
        float r[6];
#pragma unroll
        for (int q = 0; q < 6; ++q) {
            float s = sred[q][0][lane];
#pragma unroll
            for (int k = 1; k < 4; ++k) s += sred[q][k][lane];
            r[q] = s;
        }
        float invS = 1.f / r[0];
        float outx = r[2] * invS;
        float outy = r[3] * invS;
        // sum p*log p = A/S - log S  (p = z/S, log p = d - log S)
        float lent = (logf(r[0]) - r[1] * invS) * (1.0f / logf(49.0f));
        float gent = (logf(r[4]) - r[5] / r[4]) * (1.0f / logf(81.0f));

        float* op = out0 + (size_t)bf * 4 * HW_ + pix;
        op[0 * HW_] = outx;
        op[1 * HW_] = outy;
        op[2 * HW_] = lent;
        op[3 * HW_] = gent;
    }
}

__global__ __launch_bounds__(256)
void warp_kernel(const float* __restrict__ tar,
                 const float* __restrict__ out0,
                 float* __restrict__ warped) {
    int tid = blockIdx.x * 256 + threadIdx.x;   // over B_*C_*HW_
    int pix = tid & (HW_ - 1);
    int bc  = tid >> 12;
    int b   = bc >> 7;                          // C_ = 128
    int x = pix & 63, y = pix >> 6;

    // flow = hypothesis f=0 of out0 for this b
    const float* fbase = out0 + (size_t)(b * F_) * 4 * HW_;
    float fx = fbase[pix];
    float fy = fbase[HW_ + pix];
    float px = (float)x + fx;
    float py = (float)y + fy;

    bool inb = (fabsf(2.0f * px / (float)(W_ - 1) - 1.0f) < 1.0f) &&
               (fabsf(2.0f * py / (float)(H_ - 1) - 1.0f) < 1.0f);

    float x0 = floorf(px), y0 = floorf(py);
    float wx = px - x0,    wy = py - y0;
    int x0i = (int)x0, y0i = (int)y0;

    const float* img = tar + (size_t)bc * HW_;

    auto tap = [&](int yi, int xi, float wgt) -> float {
        bool v = ((unsigned)xi < (unsigned)W_) && ((unsigned)yi < (unsigned)H_);
        int xc = xi < 0 ? 0 : (xi > W_ - 1 ? W_ - 1 : xi);
        int yc = yi < 0 ? 0 : (yi > H_ - 1 ? H_ - 1 : yi);
        float val = img[yc * W_ + xc];
        return val * (v ? wgt : 0.f);
    };

    float acc = tap(y0i,     x0i,     (1.f - wx) * (1.f - wy))
              + tap(y0i,     x0i + 1, wx * (1.f - wy))
              + tap(y0i + 1, x0i,     (1.f - wx) * wy)
              + tap(y0i + 1, x0i + 1, wx * wy);

    warped[tid] = inb ? acc : 0.f;
}

extern "C" void kernel_launch(void* const* d_in, const int* in_sizes, int n_in,
                              void* d_out, int out_size, void* d_ws, size_t ws_size,
                              hipStream_t stream) {
    const float* ref = (const float*)d_in[0];
    const float* tar = (const float*)d_in[1];
    const float* pw  = (const float*)d_in[2];
    float* out0 = (float*)d_out;                       // (B*F, 4, H, W) = 524288 floats
    float* out1 = out0 + (size_t)BF_ * 4 * HW_;        // (B, C, H, W)  = 2097152 floats
    float* cvol = (float*)d_ws;                        // 81*32*4096 floats = 42.5 MB

    dim3 gc(H_ / 4, U_, B_ * 3);                       // (row-quad, dv, b*3+ugroup)
    cvol_kernel<<<gc, 256, 0, stream>>>(ref, tar, pw, cvol);
    flowreg_kernel<<<(BF_ * HW_) / 64, 256, 0, stream>>>(cvol, out0);
    warp_kernel<<<(B_ * C_ * HW_) / 256, 256, 0, stream>>>(tar, out0, out1);
}